// Round 1
// baseline (3229.554 us; speedup 1.0000x reference)
//
#include <hip/hip_runtime.h>
#include <stdint.h>

// StackedRNN depth-3, B=16, T=2048, H=256. Inputs fp32, output fp32.
// 3 persistent workgroups (one per depth), 256 threads (4 waves, 1/SIMD).
// Each wave owns 64 output rows (4 M-tiles): weights fp16 in 256 VGPR/lane.
// Halves per-step LDS B-reads vs 8-wave version (4 x 16KB, frags held in
// regs across both MFMA passes). Dual-pass MFMA: tiles01 then tiles23 with
// tiles01 tanh/pack in the pass-2 MFMA shadow; out-store of step t-1
// deferred into step t's pass-1 shadow. Single barrier/step, XOR-swizzled
// LDS, exp2 tanh, 2-step-deep global prefetch, agent-scope progress flags.

#define TT 2048
#define HH 256

typedef _Float16 h16x8 __attribute__((ext_vector_type(8)));
typedef float f32x4 __attribute__((ext_vector_type(4)));

__device__ __forceinline__ unsigned pkrtz(float a, float b) {
  return __builtin_bit_cast(unsigned, __builtin_amdgcn_cvt_pkrtz(a, b));
}

// tanh(x) = 1 - 2e/(1+e), e = e^{-2x} = exp2(-2*log2(e)*x).  ~1e-6 err.
__device__ __forceinline__ float tanh_fast(float x) {
  float xm = fmaxf(x, -15.0f);
  float e = __builtin_amdgcn_exp2f(xm * -2.88539008177793f);
  float r = __builtin_amdgcn_rcpf(1.0f + e);
  return __builtin_fmaf(-2.0f * e, r, 1.0f);
}

__device__ __forceinline__ void spin_ge(int* p, int need) {
  while (__hip_atomic_load(p, __ATOMIC_ACQUIRE, __HIP_MEMORY_SCOPE_AGENT) < need)
    __builtin_amdgcn_s_sleep(2);
}

// LDS B layout (fp16, K=512 = [inp 256 | h 256]):
//   granule (16B) for (k,n): u = (k>>5)*4 + ((k>>3)&3), v = n, j = k&7
//   half-index = (u*16 + (v ^ (u&7)))*8 + j
__global__ __launch_bounds__(256, 1)
void stacked_rnn(const float* __restrict__ x,
                 const int* __restrict__ seq_lens,
                 const float* __restrict__ Wih,
                 const float* __restrict__ Whh,
                 const float* __restrict__ bias,
                 float* __restrict__ out,
                 int* flags) {
  const int ks = blockIdx.x;           // depth stage 0..2
  const int tid = (int)threadIdx.x;
  const int w = tid >> 6;              // wave 0..3 -> rows [64w, 64w+64)
  const int lane = tid & 63;
  const int q = lane >> 4;
  const int n = lane & 15;             // batch column

  __shared__ __align__(16) unsigned short Bsm[2][8192];  // 2 x 16KB ping-pong

  int* flag_up = flags + (ks - 1) * 64;
  int* flag_me = flags + ks * 64;

  // ---- persistent weight A-fragments (fp16): kt<8 = W_ih, kt>=8 = W_hh
  h16x8 wf[4][16];
  {
    const float* wih_s = Wih + ks * (HH * HH);
    const float* whh_s = Whh + ks * (HH * HH);
#pragma unroll
    for (int mti = 0; mti < 4; ++mti) {
      const int fA = w * 64 + mti * 16 + n;      // A row = lane&15
#pragma unroll
      for (int kt = 0; kt < 16; ++kt) {
        const int col = (kt & 7) * 32 + q * 8;   // A k = quad*8 + j
        const float* src = (kt < 8) ? (wih_s + fA * HH + col)
                                    : (whh_s + fA * HH + col);
        float4 a0 = ((const float4*)src)[0];
        float4 a1 = ((const float4*)src)[1];
        h16x8 f;
        f[0] = (_Float16)a0.x; f[1] = (_Float16)a0.y;
        f[2] = (_Float16)a0.z; f[3] = (_Float16)a0.w;
        f[4] = (_Float16)a1.x; f[5] = (_Float16)a1.y;
        f[6] = (_Float16)a1.z; f[7] = (_Float16)a1.w;
        wf[mti][kt] = f;
      }
    }
  }

  // ---- bias in C-layout (row = q*4+r, col = n)
  f32x4 biasv[4];
#pragma unroll
  for (int mti = 0; mti < 4; ++mti)
#pragma unroll
    for (int r = 0; r < 4; ++r)
      biasv[mti][r] = bias[ks * HH + w * 64 + mti * 16 + q * 4 + r];

  const int sl = seq_lens[n];

  // ---- fragment read offsets (halves): frag kt at rd{E,O} + kt*512
  const int rdE = (q * 16 + (n ^ q)) * 8;        // even kt: u&7 = q
  const int rdO = (q * 16 + (n ^ q ^ 4)) * 8;    // odd  kt: u&7 = q+4

  // ---- h-repack write offsets (uint2 = 4 halves, j0 = (q&1)*4)
  int hofs[4];
#pragma unroll
  for (int mti = 0; mti < 4; ++mti) {
    const int u = (8 + 2 * w + (mti >> 1)) * 4 + 2 * (mti & 1) + (q >> 1);
    hofs[mti] = (u * 16 + (n ^ (u & 7))) * 8 + (q & 1) * 4;
  }

  // ---- loader: 512 chunks of 8 floats; thread handles (n0,k8) and (n0+8,k8)
  const int n0 = tid >> 5;
  const int k8 = tid & 31;
  const int uL = (k8 >> 2) * 4 + (k8 & 3);
  const int ldstA = (uL * 16 + (n0 ^ (uL & 7))) * 8;
  const int ldstB = (uL * 16 + ((n0 + 8) ^ (uL & 7))) * 8;

  const float* srcA;
  const float* srcB;
  int src_stride;
  if (ks == 0) {
    srcA = x + ((n0 * TT) << 8) + (k8 << 3);
    srcB = x + (((n0 + 8) * TT) << 8) + (k8 << 3);
    src_stride = HH;
  } else {
    srcA = out + (((n0 * TT) * 3 + (ks - 1)) << 8) + (k8 << 3);
    srcB = out + ((((n0 + 8) * TT) * 3 + (ks - 1)) << 8) + (k8 << 3);
    src_stride = 3 * HH;
  }

  // ---- zero h-half of buf0 (h_{-1} = 0)
#pragma unroll
  for (int i = 0; i < 2; ++i)
    ((uint4*)&Bsm[0][4096])[tid + 256 * i] = make_uint4(0, 0, 0, 0);
  if (ks > 0 && tid == 0) spin_ge(flag_up, 18);   // covers preload + early loads
  __syncthreads();

  // ---- preload inp_0 -> buf0; inp_1 pre-packed in ipk; pf pointer at t=2
  uint4 ipkA, ipkB;
  {
    float4 a0 = ((const float4*)srcA)[0];
    float4 a1 = ((const float4*)srcA)[1];
    *(uint4*)&Bsm[0][ldstA] = make_uint4(pkrtz(a0.x, a0.y), pkrtz(a0.z, a0.w),
                                         pkrtz(a1.x, a1.y), pkrtz(a1.z, a1.w));
    float4 b0 = ((const float4*)srcB)[0];
    float4 b1 = ((const float4*)srcB)[1];
    *(uint4*)&Bsm[0][ldstB] = make_uint4(pkrtz(b0.x, b0.y), pkrtz(b0.z, b0.w),
                                         pkrtz(b1.x, b1.y), pkrtz(b1.z, b1.w));
    float4 c0 = ((const float4*)(srcA + src_stride))[0];
    float4 c1 = ((const float4*)(srcA + src_stride))[1];
    ipkA = make_uint4(pkrtz(c0.x, c0.y), pkrtz(c0.z, c0.w),
                      pkrtz(c1.x, c1.y), pkrtz(c1.z, c1.w));
    float4 d0 = ((const float4*)(srcB + src_stride))[0];
    float4 d1 = ((const float4*)(srcB + src_stride))[1];
    ipkB = make_uint4(pkrtz(d0.x, d0.y), pkrtz(d0.z, d0.w),
                      pkrtz(d1.x, d1.y), pkrtz(d1.z, d1.w));
  }
  const float* pfsA = srcA + 2 * src_stride;
  const float* pfsB = srcB + 2 * src_stride;
  __syncthreads();

  float* outp_st = out + ((n * TT) * 3 + ks) * HH + w * 64 + q * 4;
  float hv[16];   // step-t tanh results, stored (masked) during step t+1
  bool lp = true; // liveness mask of step t-1

  for (int t = 0; t < TT; ++t) {
    unsigned short* Bp = Bsm[t & 1];
    unsigned short* Bq = Bsm[(t & 1) ^ 1];

    // ---- publish: steps <= t-2 are store-issued AND barrier-ordered here
    if ((t & 7) == 0 && t > 0 && ks < 2 && tid == 0)
      __hip_atomic_store(flag_me, t - 1, __ATOMIC_RELEASE,
                         __HIP_MEMORY_SCOPE_AGENT);
    // ---- chunk gate: iters t..t+15 load steps t+2..t+17 -> need flag t+18
    if ((t & 15) == 0 && t > 0 && ks > 0) {
      if (tid == 0) {
        int need = t + 18;
        if (need > TT) need = TT;
        spin_ge(flag_up, need);
      }
      __syncthreads();
    }

    const bool more2 = (t + 2 < TT);
    float4 pfA0, pfA1, pfA2, pfA3;

    h16x8 bfr[16];
    f32x4 acc[4] = {biasv[0], biasv[1], biasv[2], biasv[3]};

    // ---- pass 1: tiles 0,1 (+ issue global prefetch for inp_{t+2})
#pragma unroll
    for (int kt = 0; kt < 16; ++kt) {
      const int ofs = ((kt & 1) ? rdO : rdE) + kt * 512;
      bfr[kt] = *(const h16x8*)&Bp[ofs];
      acc[0] = __builtin_amdgcn_mfma_f32_16x16x32_f16(wf[0][kt], bfr[kt], acc[0], 0, 0, 0);
      acc[1] = __builtin_amdgcn_mfma_f32_16x16x32_f16(wf[1][kt], bfr[kt], acc[1], 0, 0, 0);
      if (kt == 0 && more2) {
        pfA0 = ((const float4*)pfsA)[0];
        pfA1 = ((const float4*)pfsA)[1];
        pfA2 = ((const float4*)pfsB)[0];
        pfA3 = ((const float4*)pfsB)[1];
      }
    }
    pfsA += src_stride;
    pfsB += src_stride;

    // ---- deferred masked fp32 out-store for step t-1 (MFMA shadow)
    if (t) {
#pragma unroll
      for (int mti = 0; mti < 4; ++mti) {
        float4 od;
        od.x = lp ? hv[mti * 4 + 0] : 0.0f;
        od.y = lp ? hv[mti * 4 + 1] : 0.0f;
        od.z = lp ? hv[mti * 4 + 2] : 0.0f;
        od.w = lp ? hv[mti * 4 + 3] : 0.0f;
        *(float4*)(outp_st + mti * 16) = od;
      }
      outp_st += 3 * HH;
    }

    uint2 hpk[4];
    // ---- pass 2: tiles 2,3 (+ tanh/pack of tiles 0,1 in the MFMA shadow)
#pragma unroll
    for (int kt = 0; kt < 16; ++kt) {
      acc[2] = __builtin_amdgcn_mfma_f32_16x16x32_f16(wf[2][kt], bfr[kt], acc[2], 0, 0, 0);
      acc[3] = __builtin_amdgcn_mfma_f32_16x16x32_f16(wf[3][kt], bfr[kt], acc[3], 0, 0, 0);
      if (kt < 8) hv[kt] = tanh_fast(acc[kt >> 2][kt & 3]);
      if (kt == 8)  { hpk[0].x = pkrtz(hv[0], hv[1]); hpk[0].y = pkrtz(hv[2], hv[3]); }
      if (kt == 9)  { hpk[1].x = pkrtz(hv[4], hv[5]); hpk[1].y = pkrtz(hv[6], hv[7]); }
    }

    // ---- tail: tanh tiles 2,3 + repack + LDS writes
#pragma unroll
    for (int j = 0; j < 8; ++j) hv[8 + j] = tanh_fast(acc[2 + (j >> 2)][j & 3]);
    hpk[2].x = pkrtz(hv[8], hv[9]);
    hpk[2].y = pkrtz(hv[10], hv[11]);
    hpk[3].x = pkrtz(hv[12], hv[13]);
    hpk[3].y = pkrtz(hv[14], hv[15]);

    if (t + 1 < TT) {
      *(uint4*)&Bq[ldstA] = ipkA;       // inp_{t+1} (pre-packed last iter)
      *(uint4*)&Bq[ldstB] = ipkB;
      *(uint2*)&Bq[hofs[0]] = hpk[0];   // h_t repack
      *(uint2*)&Bq[hofs[1]] = hpk[1];
      *(uint2*)&Bq[hofs[2]] = hpk[2];
      *(uint2*)&Bq[hofs[3]] = hpk[3];
    }
    if (more2) {                        // pack inp_{t+2} for next iter's write
      ipkA = make_uint4(pkrtz(pfA0.x, pfA0.y), pkrtz(pfA0.z, pfA0.w),
                        pkrtz(pfA1.x, pfA1.y), pkrtz(pfA1.z, pfA1.w));
      ipkB = make_uint4(pkrtz(pfA2.x, pfA2.y), pkrtz(pfA2.z, pfA2.w),
                        pkrtz(pfA3.x, pfA3.y), pkrtz(pfA3.z, pfA3.w));
    }
    lp = (t < sl);
    __syncthreads();   // the one per-step barrier
  }

  // ---- epilogue: store step TT-1, then publish completion
#pragma unroll
  for (int mti = 0; mti < 4; ++mti) {
    float4 od;
    od.x = lp ? hv[mti * 4 + 0] : 0.0f;
    od.y = lp ? hv[mti * 4 + 1] : 0.0f;
    od.z = lp ? hv[mti * 4 + 2] : 0.0f;
    od.w = lp ? hv[mti * 4 + 3] : 0.0f;
    *(float4*)(outp_st + mti * 16) = od;
  }
  __syncthreads();     // order all waves' final stores before the flush
  if (ks < 2 && tid == 0)
    __hip_atomic_store(flag_me, TT, __ATOMIC_RELEASE, __HIP_MEMORY_SCOPE_AGENT);
}

extern "C" void kernel_launch(void* const* d_in, const int* in_sizes, int n_in,
                              void* d_out, int out_size, void* d_ws, size_t ws_size,
                              hipStream_t stream) {
  (void)in_sizes; (void)n_in; (void)out_size; (void)ws_size;
  const float* x   = (const float*)d_in[0];
  const int*   sl  = (const int*)d_in[1];
  const float* wih = (const float*)d_in[2];
  const float* whh = (const float*)d_in[3];
  const float* b   = (const float*)d_in[4];

  // zero the progress flags (ws is poisoned 0xAA before every launch)
  (void)hipMemsetAsync(d_ws, 0, 1024, stream);
  hipLaunchKernelGGL(stacked_rnn, dim3(3), dim3(256), 0, stream,
                     x, sl, wih, whh, b, (float*)d_out, (int*)d_ws);
}

// Round 2
// 3018.624 us; speedup vs baseline: 1.0699x; 1.0699x over previous
//
#include <hip/hip_runtime.h>
#include <stdint.h>

// StackedRNN depth-3, B=16, T=2048, H=256. Inputs fp32, output fp32.
// 3 persistent workgroups (one per depth), 512 threads (8 waves, 2/SIMD).
// Weights fp16-resident (wf[2][16] = 128 regs/lane, compiler places in
// AGPR side), batch=16 in MFMA N, depth pipelined via agent-scope flags.
// Single barrier/step, XOR-swizzled LDS (conflict-free), exp2 tanh,
// 2-step-deep global prefetch. This round: deferred out-store (step t-1
// stored inside step t's MFMA issue window) + pre-packed inp (fp16 pack
// in MFMA shadow) to shrink the exposed per-step tail.

#define TT 2048
#define HH 256

typedef _Float16 h16x8 __attribute__((ext_vector_type(8)));
typedef float f32x4 __attribute__((ext_vector_type(4)));

__device__ __forceinline__ unsigned pkrtz(float a, float b) {
  return __builtin_bit_cast(unsigned, __builtin_amdgcn_cvt_pkrtz(a, b));
}

// tanh(x) = 1 - 2e/(1+e), e = e^{-2x} = exp2(-2*log2(e)*x).  ~1e-6 err.
__device__ __forceinline__ float tanh_fast(float x) {
  float xm = fmaxf(x, -15.0f);
  float e = __builtin_amdgcn_exp2f(xm * -2.88539008177793f);
  float r = __builtin_amdgcn_rcpf(1.0f + e);
  return __builtin_fmaf(-2.0f * e, r, 1.0f);
}

__device__ __forceinline__ void spin_ge(int* p, int need) {
  while (__hip_atomic_load(p, __ATOMIC_ACQUIRE, __HIP_MEMORY_SCOPE_AGENT) < need)
    __builtin_amdgcn_s_sleep(2);
}

// LDS B layout (fp16, K=512 = [inp 256 | h 256]):
//   granule (16B) for (k,n): u = (k>>5)*4 + ((k>>3)&3), v = n, j = k&7
//   half-index = (u*16 + (v ^ (u&7)))*8 + j     (XOR swizzle kills write
//   conflicts; reads at fixed u keep all 16 v' distinct -> conflict-free)
__global__ __launch_bounds__(512, 2)
void stacked_rnn(const float* __restrict__ x,
                 const int* __restrict__ seq_lens,
                 const float* __restrict__ Wih,
                 const float* __restrict__ Whh,
                 const float* __restrict__ bias,
                 float* __restrict__ out,
                 int* flags) {
  const int ks = blockIdx.x;           // depth stage 0..2
  const int tid = (int)threadIdx.x;
  const int w = tid >> 6;              // wave 0..7 -> rows [32w, 32w+32)
  const int lane = tid & 63;
  const int q = lane >> 4;
  const int n = lane & 15;             // batch column

  __shared__ __align__(16) unsigned short Bsm[2][8192];  // 2 x 16KB ping-pong

  int* flag_up = flags + (ks - 1) * 64;
  int* flag_me = flags + ks * 64;

  // ---- persistent weight A-fragments (fp16, RTN): kt<8 = W_ih, kt>=8 = W_hh
  h16x8 wf[2][16];
  {
    const float* wih_s = Wih + ks * (HH * HH);
    const float* whh_s = Whh + ks * (HH * HH);
#pragma unroll
    for (int mti = 0; mti < 2; ++mti) {
      const int fA = w * 32 + mti * 16 + n;      // A row = lane&15
#pragma unroll
      for (int kt = 0; kt < 16; ++kt) {
        const int col = (kt & 7) * 32 + q * 8;   // A k = quad*8 + j
        const float* src = (kt < 8) ? (wih_s + fA * HH + col)
                                    : (whh_s + fA * HH + col);
        float4 a0 = ((const float4*)src)[0];
        float4 a1 = ((const float4*)src)[1];
        h16x8 f;
        f[0] = (_Float16)a0.x; f[1] = (_Float16)a0.y;
        f[2] = (_Float16)a0.z; f[3] = (_Float16)a0.w;
        f[4] = (_Float16)a1.x; f[5] = (_Float16)a1.y;
        f[6] = (_Float16)a1.z; f[7] = (_Float16)a1.w;
        wf[mti][kt] = f;
      }
    }
  }

  // ---- bias in C-layout (row = q*4+r, col = n), exact fp32
  f32x4 biasv[2];
#pragma unroll
  for (int mti = 0; mti < 2; ++mti)
#pragma unroll
    for (int r = 0; r < 4; ++r)
      biasv[mti][r] = bias[ks * HH + w * 32 + mti * 16 + q * 4 + r];

  const int sl = seq_lens[n];

  // ---- fragment read offsets (halves): frag kt at rd{E,O} + kt*512
  const int rdE = (q * 16 + (n ^ q)) * 8;        // even kt: u&7 = q
  const int rdO = (q * 16 + (n ^ q ^ 4)) * 8;    // odd  kt: u&7 = q+4

  // ---- h-repack write offsets (uint2 = 4 halves, j0 = (q&1)*4)
  int hofs[2];
#pragma unroll
  for (int mti = 0; mti < 2; ++mti) {
    const int u = (8 + w) * 4 + mti * 2 + (q >> 1);
    hofs[mti] = (u * 16 + (n ^ (u & 7))) * 8 + (q & 1) * 4;
  }

  // ---- loader: 512 chunks of 8 floats = {n 0..15} x {k8 0..31}, 1/thread
  const int n_l = tid >> 5;
  const int k8  = tid & 31;
  const int u_l = (k8 >> 2) * 4 + (k8 & 3);
  const int ldst = (u_l * 16 + (n_l ^ (u_l & 7))) * 8;

  const float* src_base;
  int src_stride;
  if (ks == 0) {
    src_base = x + ((n_l * TT) << 8) + (k8 << 3);
    src_stride = HH;
  } else {
    src_base = out + (((n_l * TT) * 3 + (ks - 1)) << 8) + (k8 << 3);
    src_stride = 3 * HH;
  }

  // ---- zero h-half of buf0 (h_{-1} = 0): 8KB, one b128 store per thread
  ((uint4*)&Bsm[0][4096])[tid] = make_uint4(0, 0, 0, 0);
  if (ks > 0 && tid == 0) spin_ge(flag_up, 18);   // covers preload + chunk 0
  __syncthreads();

  // ---- preload inp_0 -> buf0; inp_1 pre-packed in ipk; pf pointer at t=2
  uint4 ipk;
  {
    float4 c0 = ((const float4*)src_base)[0];
    float4 c1 = ((const float4*)src_base)[1];
    *(uint4*)&Bsm[0][ldst] = make_uint4(pkrtz(c0.x, c0.y), pkrtz(c0.z, c0.w),
                                        pkrtz(c1.x, c1.y), pkrtz(c1.z, c1.w));
    float4 d0 = ((const float4*)(src_base + src_stride))[0];
    float4 d1 = ((const float4*)(src_base + src_stride))[1];
    ipk = make_uint4(pkrtz(d0.x, d0.y), pkrtz(d0.z, d0.w),
                     pkrtz(d1.x, d1.y), pkrtz(d1.z, d1.w));
  }
  const float* src_pf = src_base + 2 * src_stride;
  __syncthreads();

  float* outp_st = out + ((n * TT) * 3 + ks) * HH + w * 32 + q * 4;
  float hv[8];    // step-t tanh results, stored (masked) during step t+1
  bool lp = true; // liveness mask of step t-1

  for (int t = 0; t < TT; ++t) {
    unsigned short* Bp = Bsm[t & 1];
    unsigned short* Bq = Bsm[(t & 1) ^ 1];

    // ---- publish: steps <= t-2 are store-issued AND barrier-ordered here
    if ((t & 7) == 0 && t > 0 && ks < 2 && tid == 0)
      __hip_atomic_store(flag_me, t - 1, __ATOMIC_RELEASE,
                         __HIP_MEMORY_SCOPE_AGENT);
    // ---- chunk gate: iters t..t+15 load steps t+2..t+17 -> need flag t+18
    if ((t & 15) == 0 && t > 0 && ks > 0) {
      if (tid == 0) {
        int need = t + 18;
        if (need > TT) need = TT;
        spin_ge(flag_up, need);
      }
      __syncthreads();
    }

    // ---- deferred masked fp32 out-store for step t-1 (MFMA issue window)
    if (t) {
#pragma unroll
      for (int mti = 0; mti < 2; ++mti) {
        float4 od;
        od.x = lp ? hv[mti * 4 + 0] : 0.0f;
        od.y = lp ? hv[mti * 4 + 1] : 0.0f;
        od.z = lp ? hv[mti * 4 + 2] : 0.0f;
        od.w = lp ? hv[mti * 4 + 3] : 0.0f;
        *(float4*)(outp_st + mti * 16) = od;
      }
      outp_st += 3 * HH;
    }

    // ---- issue global prefetch for inp_{t+2} (drained at this iter's barrier)
    float4 pfA0, pfA1;
    const bool more2 = (t + 2 < TT);
    if (more2) {
      pfA0 = ((const float4*)src_pf)[0];
      pfA1 = ((const float4*)src_pf)[1];
    }
    src_pf += src_stride;

    // ---- GEMM: acc = bias + Wcat @ [inp_t ; h_{t-1}]
    f32x4 acc[2] = {biasv[0], biasv[1]};
#pragma unroll
    for (int kt = 0; kt < 16; ++kt) {
      const int ofs = ((kt & 1) ? rdO : rdE) + kt * 512;
      h16x8 bf = *(const h16x8*)&Bp[ofs];
      acc[0] = __builtin_amdgcn_mfma_f32_16x16x32_f16(wf[0][kt], bf, acc[0], 0, 0, 0);
      acc[1] = __builtin_amdgcn_mfma_f32_16x16x32_f16(wf[1][kt], bf, acc[1], 0, 0, 0);
    }

    // ---- tail: tanh + pack h_t (store deferred to next iter)
    uint2 hpk[2];
#pragma unroll
    for (int mti = 0; mti < 2; ++mti) {
      float h0 = tanh_fast(acc[mti][0]);
      float h1 = tanh_fast(acc[mti][1]);
      float h2 = tanh_fast(acc[mti][2]);
      float h3 = tanh_fast(acc[mti][3]);
      hv[mti * 4 + 0] = h0;
      hv[mti * 4 + 1] = h1;
      hv[mti * 4 + 2] = h2;
      hv[mti * 4 + 3] = h3;
      hpk[mti].x = pkrtz(h0, h1);
      hpk[mti].y = pkrtz(h2, h3);
    }

    // ---- write buf p^1: inp_{t+1} (pre-packed) + h_t (repack)
    if (t + 1 < TT) {
      *(uint4*)&Bq[ldst] = ipk;
      *(uint2*)&Bq[hofs[0]] = hpk[0];
      *(uint2*)&Bq[hofs[1]] = hpk[1];
    }
    if (more2) {                        // pack inp_{t+2} for next iter's write
      ipk = make_uint4(pkrtz(pfA0.x, pfA0.y), pkrtz(pfA0.z, pfA0.w),
                       pkrtz(pfA1.x, pfA1.y), pkrtz(pfA1.z, pfA1.w));
    }
    lp = (t < sl);
    __syncthreads();   // the one per-step barrier
  }

  // ---- epilogue: store step TT-1, then publish completion
#pragma unroll
  for (int mti = 0; mti < 2; ++mti) {
    float4 od;
    od.x = lp ? hv[mti * 4 + 0] : 0.0f;
    od.y = lp ? hv[mti * 4 + 1] : 0.0f;
    od.z = lp ? hv[mti * 4 + 2] : 0.0f;
    od.w = lp ? hv[mti * 4 + 3] : 0.0f;
    *(float4*)(outp_st + mti * 16) = od;
  }
  __syncthreads();     // order all waves' final stores before the flush
  if (ks < 2 && tid == 0)
    __hip_atomic_store(flag_me, TT, __ATOMIC_RELEASE, __HIP_MEMORY_SCOPE_AGENT);
}

extern "C" void kernel_launch(void* const* d_in, const int* in_sizes, int n_in,
                              void* d_out, int out_size, void* d_ws, size_t ws_size,
                              hipStream_t stream) {
  (void)in_sizes; (void)n_in; (void)out_size; (void)ws_size;
  const float* x   = (const float*)d_in[0];
  const int*   sl  = (const int*)d_in[1];
  const float* wih = (const float*)d_in[2];
  const float* whh = (const float*)d_in[3];
  const float* b   = (const float*)d_in[4];

  // zero the progress flags (ws is poisoned 0xAA before every launch)
  (void)hipMemsetAsync(d_ws, 0, 1024, stream);
  hipLaunchKernelGGL(stacked_rnn, dim3(3), dim3(512), 0, stream,
                     x, sl, wih, whh, b, (float*)d_out, (int*)d_ws);
}

// Round 3
// 2243.245 us; speedup vs baseline: 1.4397x; 1.3457x over previous
//
#include <hip/hip_runtime.h>
#include <stdint.h>

// StackedRNN depth-3, B=16, T=2048, H=256. Inputs fp32, output fp32.
// 3 persistent workgroups (one per depth), 512 threads (8 waves, 2/SIMD).
// Weights fp16-resident in VGPRs (wf[2][16] = 128 VGPR/lane), batch=16 in
// MFMA N, depth pipelined through d_out with agent-scope progress flags.
// Single barrier/step (ping-pong LDS B), XOR-swizzled LDS (conflict-free),
// exp2-based tanh, 2-step-deep global prefetch.
// This round (vs verified 2303us baseline): LIGHT per-step barrier
// (expcnt/lgkmcnt only, NO vmcnt drain) on 7 of 8 steps; full
// __syncthreads() at (t&7)==7 so the flag publish at t%8==0 still has all
// threads' out-stores drained. Loop body otherwise byte-identical.

#define TT 2048
#define HH 256

typedef _Float16 h16x8 __attribute__((ext_vector_type(8)));
typedef float f32x4 __attribute__((ext_vector_type(4)));

__device__ __forceinline__ unsigned pkrtz(float a, float b) {
  return __builtin_bit_cast(unsigned, __builtin_amdgcn_cvt_pkrtz(a, b));
}

// tanh(x) = 1 - 2e/(1+e), e = e^{-2x} = exp2(-2*log2(e)*x).  ~1e-6 err.
// clamp low side so e stays finite (avoids inf*0 NaN).
__device__ __forceinline__ float tanh_fast(float x) {
  float xm = fmaxf(x, -15.0f);
  float e = __builtin_amdgcn_exp2f(xm * -2.88539008177793f);
  float r = __builtin_amdgcn_rcpf(1.0f + e);
  return __builtin_fmaf(-2.0f * e, r, 1.0f);
}

__device__ __forceinline__ void spin_ge(int* p, int need) {
  while (__hip_atomic_load(p, __ATOMIC_ACQUIRE, __HIP_MEMORY_SCOPE_AGENT) < need)
    __builtin_amdgcn_s_sleep(2);
}

// Light barrier: order LDS writes (lgkmcnt) + store-data reads (expcnt)
// but leave global loads/stores in flight across the barrier (T4: never
// drain vmcnt in the main loop). "memory" clobber pins memory-op order.
__device__ __forceinline__ void light_barrier() {
  asm volatile("s_waitcnt expcnt(0) lgkmcnt(0)" ::: "memory");
  __builtin_amdgcn_s_barrier();
}

// LDS B layout (fp16, K=512 = [inp 256 | h 256]):
//   granule (16B) for (k,n): u = (k>>5)*4 + ((k>>3)&3), v = n, j = k&7
//   half-index = (u*16 + (v ^ (u&7)))*8 + j     (XOR swizzle kills write
//   conflicts; reads at fixed u keep all 16 v' distinct -> conflict-free)
__global__ __launch_bounds__(512, 2)
void stacked_rnn(const float* __restrict__ x,
                 const int* __restrict__ seq_lens,
                 const float* __restrict__ Wih,
                 const float* __restrict__ Whh,
                 const float* __restrict__ bias,
                 float* __restrict__ out,
                 int* flags) {
  const int ks = blockIdx.x;           // depth stage 0..2
  const int tid = (int)threadIdx.x;
  const int w = tid >> 6;              // wave 0..7 -> rows [32w, 32w+32)
  const int lane = tid & 63;
  const int q = lane >> 4;
  const int n = lane & 15;             // batch column

  __shared__ __align__(16) unsigned short Bsm[2][8192];   // 2 x 16KB ping-pong

  int* flag_up = flags + (ks - 1) * 64;
  int* flag_me = flags + ks * 64;

  // ---- persistent weight A-fragments (fp16, RTN): kt<8 = W_ih, kt>=8 = W_hh
  h16x8 wf[2][16];
  {
    const float* wih_s = Wih + ks * (HH * HH);
    const float* whh_s = Whh + ks * (HH * HH);
#pragma unroll
    for (int mti = 0; mti < 2; ++mti) {
      const int fA = w * 32 + mti * 16 + n;      // A row = lane&15
#pragma unroll
      for (int kt = 0; kt < 16; ++kt) {
        const int col = (kt & 7) * 32 + q * 8;   // A k = quad*8 + j
        const float* src = (kt < 8) ? (wih_s + fA * HH + col)
                                    : (whh_s + fA * HH + col);
        float4 a0 = ((const float4*)src)[0];
        float4 a1 = ((const float4*)src)[1];
        h16x8 f;
        f[0] = (_Float16)a0.x; f[1] = (_Float16)a0.y;
        f[2] = (_Float16)a0.z; f[3] = (_Float16)a0.w;
        f[4] = (_Float16)a1.x; f[5] = (_Float16)a1.y;
        f[6] = (_Float16)a1.z; f[7] = (_Float16)a1.w;
        wf[mti][kt] = f;
      }
    }
  }

  // ---- bias in C-layout (row = q*4+r, col = n), exact fp32
  f32x4 biasv[2];
#pragma unroll
  for (int mti = 0; mti < 2; ++mti)
#pragma unroll
    for (int r = 0; r < 4; ++r)
      biasv[mti][r] = bias[ks * HH + w * 32 + mti * 16 + q * 4 + r];

  const int sl = seq_lens[n];

  // ---- fragment read offsets (halves): frag kt at rd{E,O} + kt*512
  const int rdE = (q * 16 + (n ^ q)) * 8;        // even kt: u&7 = q
  const int rdO = (q * 16 + (n ^ q ^ 4)) * 8;    // odd  kt: u&7 = q+4

  // ---- h-repack write offsets (uint2 = 4 halves, j0 = (q&1)*4)
  int hofs[2];
#pragma unroll
  for (int mti = 0; mti < 2; ++mti) {
    const int u = (8 + w) * 4 + mti * 2 + (q >> 1);
    hofs[mti] = (u * 16 + (n ^ (u & 7))) * 8 + (q & 1) * 4;
  }

  // ---- loader: 512 chunks of 8 floats = {n 0..15} x {k8 0..31}, 1/thread
  const int n_l = tid >> 5;
  const int k8  = tid & 31;
  const int u_l = (k8 >> 2) * 4 + (k8 & 3);
  const int ldst = (u_l * 16 + (n_l ^ (u_l & 7))) * 8;

  const float* src_base;
  int src_stride;
  if (ks == 0) {
    src_base = x + ((n_l * TT) << 8) + (k8 << 3);
    src_stride = HH;
  } else {
    src_base = out + (((n_l * TT) * 3 + (ks - 1)) << 8) + (k8 << 3);
    src_stride = 3 * HH;
  }

  // ---- zero h-half of buf0 (h_{-1} = 0): 8KB, one b128 store per thread
  ((uint4*)&Bsm[0][4096])[tid] = make_uint4(0, 0, 0, 0);
  if (ks > 0 && tid == 0) spin_ge(flag_up, 18);   // covers preload + chunk 0
  __syncthreads();

  // ---- preload inp_0 -> buf0, inp_1 -> pfB, pf pointer at t=2
  {
    float4 c0 = ((const float4*)src_base)[0];
    float4 c1 = ((const float4*)src_base)[1];
    *(uint4*)&Bsm[0][ldst] = make_uint4(pkrtz(c0.x, c0.y), pkrtz(c0.z, c0.w),
                                        pkrtz(c1.x, c1.y), pkrtz(c1.z, c1.w));
  }
  float4 pfB0 = ((const float4*)(src_base + src_stride))[0];
  float4 pfB1 = ((const float4*)(src_base + src_stride))[1];
  const float* src_pf = src_base + 2 * src_stride;
  __syncthreads();

  float* outp = out + ((n * TT) * 3 + ks) * HH + w * 32 + q * 4;

  for (int t = 0; t < TT; ++t) {
    unsigned short* Bp = Bsm[t & 1];
    unsigned short* Bq = Bsm[(t & 1) ^ 1];

    // ---- publish (multiples of 8; stores drained by the full barrier at
    //      the end of iter t-1, since (t-1)&7 == 7)
    if ((t & 7) == 0 && t > 0 && ks < 2 && tid == 0)
      __hip_atomic_store(flag_me, t, __ATOMIC_RELEASE,
                         __HIP_MEMORY_SCOPE_AGENT);
    // ---- chunk gate: iters t..t+15 load steps t+2..t+17 -> need flag t+18
    if ((t & 15) == 0 && t > 0 && ks > 0) {
      if (tid == 0) {
        int need = t + 18;
        if (need > TT) need = TT;
        spin_ge(flag_up, need);
      }
      __syncthreads();
    }

    // ---- issue global prefetch for inp_{t+2}
    float4 pfA0, pfA1;
    const bool more2 = (t + 2 < TT);
    if (more2) {
      pfA0 = ((const float4*)src_pf)[0];
      pfA1 = ((const float4*)src_pf)[1];
    }
    src_pf += src_stride;

    // ---- GEMM: acc = bias + Wcat @ [inp_t ; h_{t-1}]
    f32x4 acc[2] = {biasv[0], biasv[1]};
#pragma unroll
    for (int kt = 0; kt < 16; ++kt) {
      const int ofs = ((kt & 1) ? rdO : rdE) + kt * 512;
      h16x8 bf = *(const h16x8*)&Bp[ofs];
      acc[0] = __builtin_amdgcn_mfma_f32_16x16x32_f16(wf[0][kt], bf, acc[0], 0, 0, 0);
      acc[1] = __builtin_amdgcn_mfma_f32_16x16x32_f16(wf[1][kt], bf, acc[1], 0, 0, 0);
    }

    // ---- tanh + masked fp32 output store (h kept unmasked for recurrence)
    const bool live = (t < sl);
    uint2 hpk[2];
#pragma unroll
    for (int mti = 0; mti < 2; ++mti) {
      float h0 = tanh_fast(acc[mti][0]);
      float h1 = tanh_fast(acc[mti][1]);
      float h2 = tanh_fast(acc[mti][2]);
      float h3 = tanh_fast(acc[mti][3]);
      hpk[mti].x = pkrtz(h0, h1);
      hpk[mti].y = pkrtz(h2, h3);
      float4 od;
      od.x = live ? h0 : 0.0f;
      od.y = live ? h1 : 0.0f;
      od.z = live ? h2 : 0.0f;
      od.w = live ? h3 : 0.0f;
      *(float4*)(outp + mti * 16) = od;
    }
    outp += 3 * HH;

    // ---- write buf p^1: inp_{t+1} (from pfB) + h_t (repack)
    if (t + 1 < TT) {
      *(uint4*)&Bq[ldst] = make_uint4(pkrtz(pfB0.x, pfB0.y), pkrtz(pfB0.z, pfB0.w),
                                      pkrtz(pfB1.x, pfB1.y), pkrtz(pfB1.z, pfB1.w));
      *(uint2*)&Bq[hofs[0]] = hpk[0];
      *(uint2*)&Bq[hofs[1]] = hpk[1];
      if (more2) { pfB0 = pfA0; pfB1 = pfA1; }
    }

    // ---- the one per-step barrier: light (no vmcnt drain) except every
    //      8th step, whose full drain backs the next publish. Uniform branch.
    if ((t & 7) == 7) {
      __syncthreads();
    } else {
      light_barrier();
    }
  }

  if (ks < 2 && tid == 0)
    __hip_atomic_store(flag_me, TT, __ATOMIC_RELEASE, __HIP_MEMORY_SCOPE_AGENT);
}

extern "C" void kernel_launch(void* const* d_in, const int* in_sizes, int n_in,
                              void* d_out, int out_size, void* d_ws, size_t ws_size,
                              hipStream_t stream) {
  (void)in_sizes; (void)n_in; (void)out_size; (void)ws_size;
  const float* x   = (const float*)d_in[0];
  const int*   sl  = (const int*)d_in[1];
  const float* wih = (const float*)d_in[2];
  const float* whh = (const float*)d_in[3];
  const float* b   = (const float*)d_in[4];

  // zero the progress flags (ws is poisoned 0xAA before every launch)
  (void)hipMemsetAsync(d_ws, 0, 1024, stream);
  hipLaunchKernelGGL(stacked_rnn, dim3(3), dim3(512), 0, stream,
                     x, sl, wih, whh, b, (float*)d_out, (int*)d_ws);
}